// Round 13
// baseline (132.225 us; speedup 1.0000x reference)
//
#include <hip/hip_runtime.h>
#include <math.h>

typedef _Float16 f16;
typedef _Float16 f16x2 __attribute__((ext_vector_type(2)));
typedef _Float16 f16x4 __attribute__((ext_vector_type(4)));
typedef _Float16 f16x8 __attribute__((ext_vector_type(8)));
typedef float    f32x4 __attribute__((ext_vector_type(4)));

constexpr int DIM   = 1024;
constexpr int HEADS = 16;
constexpr int HD    = 64;
constexpr int BATCH = 2;
constexpr int SEQ   = 2048;
constexpr int MTOT  = BATCH * SEQ;   // 4096
constexpr int NT2   = SEQ / 128;     // 16 staged KV tiles of 128

// exp(q.k/64) == exp2((q * log2e/64) . k): fold into Q projection scale.
#define QSCALE (1.4426950408889634f / 64.0f)

#define MFMA16(a, b, c) __builtin_amdgcn_mfma_f32_16x16x32_f16((a), (b), (c), 0, 0, 0)
#define SPLIT2(x, hh, ll) { const float _t = (x); hh = (f16)_t; ll = (f16)(_t - (float)(hh)); }

__device__ __forceinline__ void glds16(const void* g, void* l) {
    __builtin_amdgcn_global_load_lds(
        (const __attribute__((address_space(1))) void*)g,
        (__attribute__((address_space(3))) void*)l, 16, 0, 0);
}

__device__ __forceinline__ float exp2_hw(float x) {
    float r;
    asm("v_exp_f32 %0, %1" : "=v"(r) : "v"(x));   // D = 2^S0
    return r;
}

__device__ __forceinline__ f16x2 pk_f16(float a, float b) {
    return __builtin_bit_cast(f16x2, __builtin_amdgcn_cvt_pkrtz(a, b));
}

// ---------------------------------------------------------------------------
// Pre-split pass: fp32 -> f16 planes, GEMM fragment-read swizzle baked:
// within each 32-half k-tile, 8-half slot ^= ((row>>1)&3).
// x, Wq, Wk, Wv -> hi only. Wo -> hi + lo (2-term oproj).
// ---------------------------------------------------------------------------
__global__ __launch_bounds__(256) void presplit_kernel(
    const float* __restrict__ x,  const float* __restrict__ Wq,
    const float* __restrict__ Wk, const float* __restrict__ Wv,
    const float* __restrict__ Wo,
    f16* __restrict__ Xh,  f16* __restrict__ WqH, f16* __restrict__ WkH,
    f16* __restrict__ WvH, f16* __restrict__ WoH, f16* __restrict__ WoL)
{
    const int bid = blockIdx.x;
    const float* src; f16* dh; f16* dl = nullptr; int row;
    if (bid < 4096)      { src = x;  dh = Xh;  row = bid; }
    else if (bid < 5120) { src = Wq; dh = WqH; row = bid - 4096; }
    else if (bid < 6144) { src = Wk; dh = WkH; row = bid - 5120; }
    else if (bid < 7168) { src = Wv; dh = WvH; row = bid - 6144; }
    else                 { src = Wo; dh = WoH; dl = WoL; row = bid - 7168; }

    const int k = threadIdx.x * 4;
    const float4 v = *reinterpret_cast<const float4*>(&src[(size_t)row * DIM + k]);
    const int s = (row >> 1) & 3;
    const size_t o = (size_t)row * DIM + (k & ~31) + ((k & 31) ^ (s << 3));
    if (dl) {
        f16x4 h4, l4;
        SPLIT2(v.x, h4[0], l4[0]); SPLIT2(v.y, h4[1], l4[1]);
        SPLIT2(v.z, h4[2], l4[2]); SPLIT2(v.w, h4[3], l4[3]);
        *reinterpret_cast<f16x4*>(&dh[o]) = h4;
        *reinterpret_cast<f16x4*>(&dl[o]) = l4;
    } else {
        f16x4 h4;
        h4[0] = (f16)v.x; h4[1] = (f16)v.y; h4[2] = (f16)v.z; h4[3] = (f16)v.w;
        *reinterpret_cast<f16x4*>(&dh[o]) = h4;
    }
}

// ---------------------------------------------------------------------------
// Plane GEMM on pre-split swizzled f16 planes, global_load_lds staging.
// NEW: T3 2-phase double-buffered k-loop — STAGE(t+1) issued before
// compute(t), single vmcnt(0)+barrier per k-step (staging hidden under MFMA).
// BM=BN=128, BK=32, 4 waves.
// TERMS=1: acc = A@B^T (hi only), dbuf 2x8 KB planes.
// TERMS=2: acc = Ah@(Bh+Bl)^T, dbuf 2x12 KB planes.
// MODE 0: C=(acc+bias)*scale -> fp32.   MODE 3: F=(acc+bias)*scale -> f16.
// MODE 1: K hi plane [bh][kv][ d ^ ((kv&7)<<3) ]  (transposed compute)
// MODE 2: V hi plane [bh][d][ kv ^ ((d&7)<<3) ]
// ---------------------------------------------------------------------------
template <int MODE, int TERMS>
__device__ __forceinline__ void gemm_plane_body(
    const f16* __restrict__ AhG, const f16* __restrict__ BhG,
    const f16* __restrict__ BlG, const float* __restrict__ bias,
    float* __restrict__ C, f16* __restrict__ F, float scale,
    f16* __restrict__ smem)
{
    constexpr int NCH  = (TERMS == 1) ? 4 : 6;   // 512-half chunks per wave
    constexpr int BUFH = NCH * 4 * 512;          // halves per buffer

    const int tid = threadIdx.x;
    const int l   = tid & 63;
    const int w   = tid >> 6;
    const int wm  = (w >> 1) * 64;
    const int wn  = (w & 1) * 64;
    const int m0  = blockIdx.y * 128;
    const int n0  = blockIdx.x * 128;
    const int fr  = l & 15;
    const int fk  = (l >> 4) * 8;
    const int rg  = (l >> 4) * 4;
    const int fko = fk ^ (((fr >> 1) & 3) << 3);   // swizzled k-slot

    f32x4 acc[4][4] = {};

#define GSTAGE(B, K0) do {                                                  \
        _Pragma("unroll")                                                   \
        for (int j = 0; j < NCH; ++j) {                                     \
            const int c = w * NCH + j;                                      \
            const int p = c >> 3;                /* 0 Ah, 1 Bh, 2 Bl */     \
            const f16* P = (p == 0) ? AhG : (p == 1) ? BhG : BlG;           \
            const int r0 = (p == 0) ? m0 : n0;                              \
            const int row = r0 + (c & 7) * 16 + (l >> 2);                   \
            glds16(P + (size_t)row * DIM + (K0) + (l & 3) * 8,              \
                   smem + (B) * BUFH + c * 512);                            \
        }                                                                   \
    } while (0)

    GSTAGE(0, 0);
    asm volatile("s_waitcnt vmcnt(0)\ns_barrier" ::: "memory");
    int cur = 0;

    for (int k0 = 0; k0 < DIM; k0 += 32) {
        if (k0 + 32 < DIM) GSTAGE(cur ^ 1, k0 + 32);   // prefetch next k-tile

        const f16* Ah = smem + cur * BUFH;
        const f16* Bh = Ah + 4096;
        const f16* Bl = Bh + 4096;

        f16x8 ah[4], bh[4], bl[4];
        #pragma unroll
        for (int m = 0; m < 4; ++m)
            ah[m] = *reinterpret_cast<const f16x8*>(&Ah[(wm + m * 16 + fr) * 32 + fko]);
        #pragma unroll
        for (int n = 0; n < 4; ++n) {
            const int r = (wn + n * 16 + fr) * 32 + fko;
            bh[n] = *reinterpret_cast<const f16x8*>(&Bh[r]);
            if (TERMS == 2) bl[n] = *reinterpret_cast<const f16x8*>(&Bl[r]);
        }
        #pragma unroll
        for (int n = 0; n < 4; ++n) {
            #pragma unroll
            for (int m = 0; m < 4; ++m) {
                if (MODE == 1) {   // transposed: D[d][token]
                    acc[m][n] = MFMA16(bh[n], ah[m], acc[m][n]);
                } else {
                    acc[m][n] = MFMA16(ah[m], bh[n], acc[m][n]);
                    if (TERMS == 2)
                        acc[m][n] = MFMA16(ah[m], bl[n], acc[m][n]);
                }
            }
        }
        // one drain+barrier per k-step: next buf ready, all reads of cur done
        asm volatile("s_waitcnt vmcnt(0) lgkmcnt(0)\ns_barrier" ::: "memory");
        cur ^= 1;
    }
#undef GSTAGE

    if (MODE == 0 || MODE == 3) {
        #pragma unroll
        for (int n = 0; n < 4; ++n) {
            const int col  = n0 + wn + n * 16 + fr;
            const float bb = bias[col];
            #pragma unroll
            for (int m = 0; m < 4; ++m) {
                #pragma unroll
                for (int r = 0; r < 4; ++r) {
                    const int row = m0 + wm + m * 16 + rg + r;
                    const float v = (acc[m][n][r] + bb) * scale;
                    if (MODE == 0) C[(size_t)row * DIM + col] = v;
                    else           F[(size_t)row * DIM + col] = (f16)v;
                }
            }
        }
    } else if (MODE == 1) {
        constexpr int RS = 72;
        const int batch = m0 >> 11;
        const int kvg0  = m0 & 2047;
        for (int s = 0; s < 2; ++s) {
            __syncthreads();
            if ((w & 1) == s) {
                #pragma unroll
                for (int n = 0; n < 4; ++n) {
                    #pragma unroll
                    for (int m = 0; m < 4; ++m) {
                        const int kvrow = wm + m * 16 + fr;
                        const int dd    = n * 16 + rg;
                        f16x4 h4;
                        #pragma unroll
                        for (int r = 0; r < 4; ++r)
                            h4[r] = (f16)(acc[m][n][r] + bias[n0 + wn + dd + r]);
                        const int o = kvrow * RS + (dd ^ ((kvrow & 7) << 3));
                        *reinterpret_cast<f16x4*>(&smem[o]) = h4;
                    }
                }
            }
            __syncthreads();
            const size_t bh_ = (size_t)batch * HEADS + (n0 >> 6) + s;
            const int row = tid >> 1, c0 = (tid & 1) * 32;
            #pragma unroll
            for (int j = 0; j < 4; ++j) {
                const int so = row * RS + c0 + j * 8;
                const size_t go = bh_ * 131072 + (size_t)(kvg0 + row) * 64 + c0 + j * 8;
                *reinterpret_cast<f16x8*>(&F[go]) =
                    *reinterpret_cast<const f16x8*>(&smem[so]);
            }
        }
    } else {
        constexpr int RS = 136;
        const int batch = m0 >> 11;
        const int kvg0  = m0 & 2047;
        for (int s = 0; s < 2; ++s) {
            __syncthreads();
            if ((w & 1) == s) {
                #pragma unroll
                for (int n = 0; n < 4; ++n) {
                    const int d    = n * 16 + fr;
                    const float bb = bias[n0 + wn + d];
                    #pragma unroll
                    for (int m = 0; m < 4; ++m) {
                        const int kvl = wm + m * 16 + rg;
                        f16x4 h4;
                        h4[0] = (f16)(acc[m][n][0] + bb);
                        h4[1] = (f16)(acc[m][n][1] + bb);
                        h4[2] = (f16)(acc[m][n][2] + bb);
                        h4[3] = (f16)(acc[m][n][3] + bb);
                        const int o = d * RS + (kvl ^ ((d & 7) << 3));
                        *reinterpret_cast<f16x4*>(&smem[o]) = h4;
                    }
                }
            }
            __syncthreads();
            const size_t bh_ = (size_t)batch * HEADS + (n0 >> 6) + s;
            const int row = tid >> 2, c0 = (tid & 3) * 32;
            #pragma unroll
            for (int j = 0; j < 4; ++j) {
                const int so = row * RS + c0 + j * 8;
                const size_t go = bh_ * 131072 + (size_t)row * 2048 + kvg0 + c0 + j * 8;
                *reinterpret_cast<f16x8*>(&F[go]) =
                    *reinterpret_cast<const f16x8*>(&smem[so]);
            }
        }
    }
}

__global__ __launch_bounds__(256) void qkv_kernel(
    const f16* __restrict__ XhG,
    const f16* __restrict__ WqH, const float* __restrict__ bq,
    const f16* __restrict__ WkH, const float* __restrict__ bk,
    const f16* __restrict__ WvH, const float* __restrict__ bv,
    f16* __restrict__ QhG, f16* __restrict__ KhG, f16* __restrict__ VhG)
{
    __shared__ __align__(16) f16 smem[18432];  // 36 KB: 2x8 KB dbuf / repack
    if (blockIdx.z == 0)
        gemm_plane_body<3, 1>(XhG, WqH, nullptr, bq, nullptr, QhG, QSCALE, smem);
    else if (blockIdx.z == 1)
        gemm_plane_body<1, 1>(XhG, WkH, nullptr, bk, nullptr, KhG, 1.0f, smem);
    else
        gemm_plane_body<2, 1>(XhG, WvH, nullptr, bv, nullptr, VhG, 1.0f, smem);
}

__global__ __launch_bounds__(256) void oproj_kernel(
    const f16* __restrict__ OhG,
    const f16* __restrict__ WoH, const f16* __restrict__ WoL,
    const float* __restrict__ bo, float* __restrict__ out)
{
    __shared__ __align__(16) f16 smem[24576];  // 48 KB: 2x12 KB dbuf
    gemm_plane_body<0, 2>(OhG, WoH, WoL, bo, out, nullptr, 1.0f, smem);
}

// ---------------------------------------------------------------------------
// Flash attention v9 (unchanged from round 12, proven 48.8 us / 4.88e-4):
// KVBLK=128 staging, two 64-kv compute halves per staged tile, 4 waves,
// QBLK=32/wave, 512 blocks, 80 KB LDS. Pure-f16 MFMA, exp2-folded scores,
// lsum via ones-MFMA, P via per-wave LDS, XCD swizzle, setprio.
// ---------------------------------------------------------------------------
__global__ __launch_bounds__(256, 2) void attn_kernel(
    const f16* __restrict__ QhG, const f16* __restrict__ KhG,
    const f16* __restrict__ VhG, f16* __restrict__ OhG)
{
    __shared__ __align__(16) f16 lds[2][2][8192];   // 64 KB: Kh, Vh dbuf (128 kv)
    __shared__ __align__(16) f16 PL[4][2][1024];    // 16 KB per-wave P^T

    const int tid = threadIdx.x;
    const int l   = tid & 63;
    const int w   = tid >> 6;
    const int fr  = l & 15;
    const int g   = l >> 4;
    const int fk  = g * 8;
    const int rg  = g * 4;
    const int swz = (fr & 7) << 3;

    // 512 blocks, 64-block chunks per XCD (4 bh -> 2 MB K+V per XCD L2)
    const int lin  = blockIdx.x + 16 * (blockIdx.y + 16 * blockIdx.z);
    const int sid  = (lin & 7) * 64 + (lin >> 3);
    const int qblk = sid & 15;
    const int head = (sid >> 4) & 15;
    const int batch = sid >> 8;

    const int q0 = qblk * 128;
    const size_t rowbase = (size_t)batch * SEQ;
    const int hcol = head * HD;
    const size_t bhbase = ((size_t)batch * HEADS + head) * (size_t)(SEQ * HD);

    size_t kA[4], vA[4];
    #pragma unroll
    for (int c = 0; c < 4; ++c) {
        const int h0 = (w * 4 + c) * 512 + l * 8;
        kA[c] = bhbase + (size_t)h0;                               // + t*8192
        vA[c] = bhbase + (size_t)(h0 >> 7) * 2048 + (h0 & 127);    // + t*128
    }

#define STAGE(B, T) do {                                                    \
        const size_t _ko = (size_t)(T) * 8192;                              \
        const size_t _vo = (size_t)(T) * 128;                               \
        _Pragma("unroll")                                                   \
        for (int c = 0; c < 4; ++c) {                                       \
            const int lo_ = (w * 4 + c) * 512;                              \
            glds16(KhG + kA[c] + _ko, &lds[B][0][lo_]);                     \
            glds16(VhG + vA[c] + _vo, &lds[B][1][lo_]);                     \
        }                                                                   \
    } while (0)

    STAGE(0, 0);

    // Q fragments (B operand, f16, pre-scaled by log2e/64)
    f16x8 qh[2][2];
    #pragma unroll
    for (int qb = 0; qb < 2; ++qb) {
        const f16* qp = &QhG[(rowbase + q0 + w * 32 + qb * 16 + fr) * DIM + hcol];
        qh[qb][0] = *reinterpret_cast<const f16x8*>(&qp[fk]);
        qh[qb][1] = *reinterpret_cast<const f16x8*>(&qp[32 + fk]);
    }

    f16x8 onesv;
    #pragma unroll
    for (int i = 0; i < 8; ++i) onesv[i] = (f16)1.0f;

    f32x4 ls[2] = {};
    f32x4 oa[4][2] = {};

    int cur = 0;
    for (int t = 0; t < NT2; ++t) {
        asm volatile("s_waitcnt vmcnt(0) lgkmcnt(0)\ns_barrier" ::: "memory");
        if (t + 1 < NT2) STAGE(cur ^ 1, t + 1);

        #pragma unroll
        for (int hh = 0; hh < 2; ++hh) {     // two 64-kv halves
            const f16* Kh = &lds[cur][0][hh * 4096];
            const f16* Vh = &lds[cur][1][hh * 64];

            // ---- S'^T = K Q'^T ----
            f32x4 sa[4][2] = {};
            __builtin_amdgcn_s_setprio(1);
            #pragma unroll
            for (int kvb = 0; kvb < 4; ++kvb) {
                #pragma unroll
                for (int ks = 0; ks < 2; ++ks) {
                    const int o = ((kvb * 16 + fr) * 64 + ks * 32 + fk) ^ swz;
                    const f16x8 kh = *reinterpret_cast<const f16x8*>(&Kh[o]);
                    sa[kvb][0] = MFMA16(kh, qh[0][ks], sa[kvb][0]);
                    sa[kvb][1] = MFMA16(kh, qh[1][ks], sa[kvb][1]);
                }
            }
            __builtin_amdgcn_s_setprio(0);

            // ---- P = 2^s per q-stream, pack, stash in per-wave LDS ----
            f16x8 pf[2][2];
            #pragma unroll
            for (int qb = 0; qb < 2; ++qb) {
                f16* Wh = &PL[w][qb][0];
                #pragma unroll
                for (int kvb = 0; kvb < 4; ++kvb) {
                    const f16x2 p01 = pk_f16(exp2_hw(sa[kvb][qb][0]),
                                             exp2_hw(sa[kvb][qb][1]));
                    const f16x2 p23 = pk_f16(exp2_hw(sa[kvb][qb][2]),
                                             exp2_hw(sa[kvb][qb][3]));
                    f16x4 h4;
                    h4[0] = p01[0]; h4[1] = p01[1]; h4[2] = p23[0]; h4[3] = p23[1];
                    const int po = (fr * 64 + kvb * 16 + rg) ^ swz;
                    *reinterpret_cast<f16x4*>(&Wh[po]) = h4;
                }
                #pragma unroll
                for (int ks = 0; ks < 2; ++ks) {
                    const int ro = (fr * 64 + ks * 32 + fk) ^ swz;
                    pf[qb][ks] = *reinterpret_cast<const f16x8*>(&Wh[ro]);
                }
            }

            // ---- lsum += colsum(P); O^T += V^T P^T ----
            __builtin_amdgcn_s_setprio(1);
            #pragma unroll
            for (int qb = 0; qb < 2; ++qb)
                #pragma unroll
                for (int ks = 0; ks < 2; ++ks)
                    ls[qb] = MFMA16(onesv, pf[qb][ks], ls[qb]);
            #pragma unroll
            for (int db = 0; db < 4; ++db) {
                #pragma unroll
                for (int ks = 0; ks < 2; ++ks) {
                    const int vo = (db * 16 + fr) * 128 + ((ks * 32 + fk) ^ swz);
                    const f16x8 vh = *reinterpret_cast<const f16x8*>(&Vh[vo]);
                    oa[db][0] = MFMA16(vh, pf[0][ks], oa[db][0]);
                    oa[db][1] = MFMA16(vh, pf[1][ks], oa[db][1]);
                }
            }
            __builtin_amdgcn_s_setprio(0);
        }
        cur ^= 1;
    }
#undef STAGE

    // ---- epilogue: O hi plane (swizzled for oproj staging) ----
    #pragma unroll
    for (int qb = 0; qb < 2; ++qb) {
        const float inv = 1.0f / ls[qb][0];
        const size_t row = rowbase + q0 + w * 32 + qb * 16 + fr;
        const int s = ((int)row >> 1) & 3;
        #pragma unroll
        for (int db = 0; db < 4; ++db) {
            f16x4 h4;
            #pragma unroll
            for (int j = 0; j < 4; ++j) h4[j] = (f16)(oa[db][qb][j] * inv);
            const int kg = hcol + db * 16 + rg;
            const size_t o = row * DIM + (kg & ~31) + ((kg & 31) ^ (s << 3));
            *reinterpret_cast<f16x4*>(&OhG[o]) = h4;
        }
    }
}

extern "C" void kernel_launch(void* const* d_in, const int* in_sizes, int n_in,
                              void* d_out, int out_size, void* d_ws, size_t ws_size,
                              hipStream_t stream)
{
    const float* x  = (const float*)d_in[0];
    const float* Wq = (const float*)d_in[1];
    const float* bq = (const float*)d_in[2];
    const float* Wk = (const float*)d_in[3];
    const float* bk = (const float*)d_in[4];
    const float* Wv = (const float*)d_in[5];
    const float* bv = (const float*)d_in[6];
    const float* Wo = (const float*)d_in[7];
    const float* bo = (const float*)d_in[8];
    float* out = (float*)d_out;

    const size_t PS = (size_t)MTOT * DIM;   // 4,194,304 elements
    f16* QhG = (f16*)d_ws;                  // 8 MB each
    f16* KhG = QhG + PS;
    f16* VhG = KhG + PS;
    f16* XhG = VhG + PS;                    // reused as Oh after qkv
    f16* WqH = XhG + PS;                    // 2 MB each below
    f16* WkH = WqH + (size_t)DIM * DIM;
    f16* WvH = WkH + (size_t)DIM * DIM;
    f16* WoH = WvH + (size_t)DIM * DIM;
    f16* WoL = WoH + (size_t)DIM * DIM;
    f16* OhG = XhG;                         // alias: x consumed before attn

    presplit_kernel<<<8192, 256, 0, stream>>>(x, Wq, Wk, Wv, Wo,
                                              XhG, WqH, WkH, WvH, WoH, WoL);

    dim3 gqkv(DIM / 128, MTOT / 128, 3);
    qkv_kernel<<<gqkv, 256, 0, stream>>>(XhG, WqH, bq, WkH, bk, WvH, bv,
                                         QhG, KhG, VhG);

    dim3 gattn(SEQ / 128, HEADS, BATCH);
    attn_kernel<<<gattn, 256, 0, stream>>>(QhG, KhG, VhG, OhG);

    dim3 gout(DIM / 128, MTOT / 128);
    oproj_kernel<<<gout, 256, 0, stream>>>(OhG, WoH, WoL, bo, out);
}

// Round 14
// 124.667 us; speedup vs baseline: 1.0606x; 1.0606x over previous
//
#include <hip/hip_runtime.h>
#include <math.h>

typedef _Float16 f16;
typedef _Float16 f16x2 __attribute__((ext_vector_type(2)));
typedef _Float16 f16x4 __attribute__((ext_vector_type(4)));
typedef _Float16 f16x8 __attribute__((ext_vector_type(8)));
typedef float    f32x4 __attribute__((ext_vector_type(4)));

constexpr int DIM   = 1024;
constexpr int HEADS = 16;
constexpr int HD    = 64;
constexpr int BATCH = 2;
constexpr int SEQ   = 2048;
constexpr int MTOT  = BATCH * SEQ;   // 4096
constexpr int NT2   = SEQ / 128;     // 16 staged KV tiles of 128

// exp(q.k/64) == exp2((q * log2e/64) . k): fold into Q projection scale.
#define QSCALE (1.4426950408889634f / 64.0f)

#define MFMA16(a, b, c) __builtin_amdgcn_mfma_f32_16x16x32_f16((a), (b), (c), 0, 0, 0)

__device__ __forceinline__ void glds16(const void* g, void* l) {
    __builtin_amdgcn_global_load_lds(
        (const __attribute__((address_space(1))) void*)g,
        (__attribute__((address_space(3))) void*)l, 16, 0, 0);
}

__device__ __forceinline__ float exp2_hw(float x) {
    float r;
    asm("v_exp_f32 %0, %1" : "=v"(r) : "v"(x));   // D = 2^S0
    return r;
}

__device__ __forceinline__ f16x2 pk_f16(float a, float b) {
    return __builtin_bit_cast(f16x2, __builtin_amdgcn_cvt_pkrtz(a, b));
}

// ---------------------------------------------------------------------------
// Pre-split pass: fp32 -> f16 hi planes, GEMM fragment-read swizzle baked:
// within each 32-half k-tile, 8-half slot ^= ((row>>1)&3).
// All five matrices hi-only (1-term GEMMs everywhere).
// ---------------------------------------------------------------------------
__global__ __launch_bounds__(256) void presplit_kernel(
    const float* __restrict__ x,  const float* __restrict__ Wq,
    const float* __restrict__ Wk, const float* __restrict__ Wv,
    const float* __restrict__ Wo,
    f16* __restrict__ Xh,  f16* __restrict__ WqH, f16* __restrict__ WkH,
    f16* __restrict__ WvH, f16* __restrict__ WoH)
{
    const int bid = blockIdx.x;
    const float* src; f16* dh; int row;
    if (bid < 4096)      { src = x;  dh = Xh;  row = bid; }
    else if (bid < 5120) { src = Wq; dh = WqH; row = bid - 4096; }
    else if (bid < 6144) { src = Wk; dh = WkH; row = bid - 5120; }
    else if (bid < 7168) { src = Wv; dh = WvH; row = bid - 6144; }
    else                 { src = Wo; dh = WoH; row = bid - 7168; }

    const int k = threadIdx.x * 4;
    const float4 v = *reinterpret_cast<const float4*>(&src[(size_t)row * DIM + k]);
    const int s = (row >> 1) & 3;
    const size_t o = (size_t)row * DIM + (k & ~31) + ((k & 31) ^ (s << 3));
    f16x4 h4;
    h4[0] = (f16)v.x; h4[1] = (f16)v.y; h4[2] = (f16)v.z; h4[3] = (f16)v.w;
    *reinterpret_cast<f16x4*>(&dh[o]) = h4;
}

// ---------------------------------------------------------------------------
// 1-term plane GEMM, BK=64: 32 MFMAs per drain (half the barrier/drain tax
// of BK=32), 1-phase proven loop shape (R12). BM=BN=128, 4 waves.
// LDS: A tile 16 KB + B tile 16 KB (+ repack region for MODE 1/2).
// MODE 0: C=(acc+bias)*scale -> fp32.   MODE 3: F=(acc+bias)*scale -> f16.
// MODE 1: K hi plane [bh][kv][ d ^ ((kv&7)<<3) ]  (transposed compute)
// MODE 2: V hi plane [bh][d][ kv ^ ((d&7)<<3) ]
// ---------------------------------------------------------------------------
template <int MODE>
__device__ __forceinline__ void gemm_plane_body(
    const f16* __restrict__ AhG, const f16* __restrict__ BhG,
    const float* __restrict__ bias, float* __restrict__ C,
    f16* __restrict__ F, float scale, f16* __restrict__ smem)
{
    f16* Ah = smem;             // 128 x 64 halves = 16 KB
    f16* Bh = smem + 8192;      // 16 KB

    const int tid = threadIdx.x;
    const int l   = tid & 63;
    const int w   = tid >> 6;
    const int wm  = (w >> 1) * 64;
    const int wn  = (w & 1) * 64;
    const int m0  = blockIdx.y * 128;
    const int n0  = blockIdx.x * 128;
    const int fr  = l & 15;
    const int fk  = (l >> 4) * 8;
    const int rg  = (l >> 4) * 4;
    const int fko = fk ^ (((fr >> 1) & 3) << 3);   // swizzled k-slot

    f32x4 acc[4][4] = {};

    for (int k0 = 0; k0 < DIM; k0 += 64) {
        __syncthreads();
        // stage A(128x64) + B(128x64): 32 chunks of 512 halves, 8 per wave
        #pragma unroll
        for (int j = 0; j < 8; ++j) {
            const int c  = w * 8 + j;            // 0..31
            const int p  = c >> 4;               // 0 = A, 1 = B
            const int cc = c & 15;
            const f16* P = (p == 0) ? AhG : BhG;
            const int r0 = (p == 0) ? m0 : n0;
            const int row = r0 + cc * 8 + (l >> 3);
            glds16(P + (size_t)row * DIM + k0 + (l & 7) * 8, smem + c * 512);
        }
        asm volatile("s_waitcnt vmcnt(0)" ::: "memory");
        __syncthreads();

        f16x8 ah[2][4], bh[2][4];
        #pragma unroll
        for (int ks = 0; ks < 2; ++ks) {
            #pragma unroll
            for (int m = 0; m < 4; ++m)
                ah[ks][m] = *reinterpret_cast<const f16x8*>(
                    &Ah[(wm + m * 16 + fr) * 64 + ks * 32 + fko]);
            #pragma unroll
            for (int n = 0; n < 4; ++n)
                bh[ks][n] = *reinterpret_cast<const f16x8*>(
                    &Bh[(wn + n * 16 + fr) * 64 + ks * 32 + fko]);
        }
        #pragma unroll
        for (int ks = 0; ks < 2; ++ks)
            #pragma unroll
            for (int n = 0; n < 4; ++n)
                #pragma unroll
                for (int m = 0; m < 4; ++m) {
                    if (MODE == 1)   // transposed: D[d][token]
                        acc[m][n] = MFMA16(bh[ks][n], ah[ks][m], acc[m][n]);
                    else
                        acc[m][n] = MFMA16(ah[ks][m], bh[ks][n], acc[m][n]);
                }
    }

    if (MODE == 0 || MODE == 3) {
        #pragma unroll
        for (int n = 0; n < 4; ++n) {
            const int col  = n0 + wn + n * 16 + fr;
            const float bb = bias[col];
            #pragma unroll
            for (int m = 0; m < 4; ++m) {
                #pragma unroll
                for (int r = 0; r < 4; ++r) {
                    const int row = m0 + wm + m * 16 + rg + r;
                    const float v = (acc[m][n][r] + bb) * scale;
                    if (MODE == 0) C[(size_t)row * DIM + col] = v;
                    else           F[(size_t)row * DIM + col] = (f16)v;
                }
            }
        }
    } else if (MODE == 1) {
        constexpr int RS = 72;
        const int batch = m0 >> 11;
        const int kvg0  = m0 & 2047;
        for (int s = 0; s < 2; ++s) {
            __syncthreads();
            if ((w & 1) == s) {
                #pragma unroll
                for (int n = 0; n < 4; ++n) {
                    #pragma unroll
                    for (int m = 0; m < 4; ++m) {
                        const int kvrow = wm + m * 16 + fr;
                        const int dd    = n * 16 + rg;
                        f16x4 h4;
                        #pragma unroll
                        for (int r = 0; r < 4; ++r)
                            h4[r] = (f16)(acc[m][n][r] + bias[n0 + wn + dd + r]);
                        const int o = kvrow * RS + (dd ^ ((kvrow & 7) << 3));
                        *reinterpret_cast<f16x4*>(&smem[o]) = h4;
                    }
                }
            }
            __syncthreads();
            const size_t bh_ = (size_t)batch * HEADS + (n0 >> 6) + s;
            const int row = tid >> 1, c0 = (tid & 1) * 32;
            #pragma unroll
            for (int j = 0; j < 4; ++j) {
                const int so = row * RS + c0 + j * 8;
                const size_t go = bh_ * 131072 + (size_t)(kvg0 + row) * 64 + c0 + j * 8;
                *reinterpret_cast<f16x8*>(&F[go]) =
                    *reinterpret_cast<const f16x8*>(&smem[so]);
            }
        }
    } else {
        constexpr int RS = 136;
        const int batch = m0 >> 11;
        const int kvg0  = m0 & 2047;
        for (int s = 0; s < 2; ++s) {
            __syncthreads();
            if ((w & 1) == s) {
                #pragma unroll
                for (int n = 0; n < 4; ++n) {
                    const int d    = n * 16 + fr;
                    const float bb = bias[n0 + wn + d];
                    #pragma unroll
                    for (int m = 0; m < 4; ++m) {
                        const int kvl = wm + m * 16 + rg;
                        f16x4 h4;
                        h4[0] = (f16)(acc[m][n][0] + bb);
                        h4[1] = (f16)(acc[m][n][1] + bb);
                        h4[2] = (f16)(acc[m][n][2] + bb);
                        h4[3] = (f16)(acc[m][n][3] + bb);
                        const int o = d * RS + (kvl ^ ((d & 7) << 3));
                        *reinterpret_cast<f16x4*>(&smem[o]) = h4;
                    }
                }
            }
            __syncthreads();
            const size_t bh_ = (size_t)batch * HEADS + (n0 >> 6) + s;
            const int row = tid >> 2, c0 = (tid & 3) * 32;
            #pragma unroll
            for (int j = 0; j < 4; ++j) {
                const int so = row * RS + c0 + j * 8;
                const size_t go = bh_ * 131072 + (size_t)row * 2048 + kvg0 + c0 + j * 8;
                *reinterpret_cast<f16x8*>(&F[go]) =
                    *reinterpret_cast<const f16x8*>(&smem[so]);
            }
        }
    }
}

__global__ __launch_bounds__(256) void qkv_kernel(
    const f16* __restrict__ XhG,
    const f16* __restrict__ WqH, const float* __restrict__ bq,
    const f16* __restrict__ WkH, const float* __restrict__ bk,
    const f16* __restrict__ WvH, const float* __restrict__ bv,
    f16* __restrict__ QhG, f16* __restrict__ KhG, f16* __restrict__ VhG)
{
    __shared__ __align__(16) f16 smem[18432];  // 36 KB (tiles 32 KB, K-repack 36 KB)
    if (blockIdx.z == 0)
        gemm_plane_body<3>(XhG, WqH, bq, nullptr, QhG, QSCALE, smem);
    else if (blockIdx.z == 1)
        gemm_plane_body<1>(XhG, WkH, bk, nullptr, KhG, 1.0f, smem);
    else
        gemm_plane_body<2>(XhG, WvH, bv, nullptr, VhG, 1.0f, smem);
}

__global__ __launch_bounds__(256) void oproj_kernel(
    const f16* __restrict__ OhG, const f16* __restrict__ WoH,
    const float* __restrict__ bo, float* __restrict__ out)
{
    __shared__ __align__(16) f16 smem[16384];  // 32 KB
    gemm_plane_body<0>(OhG, WoH, bo, out, nullptr, 1.0f, smem);
}

// ---------------------------------------------------------------------------
// Flash attention v9 (unchanged, proven 48.8 us / 4.88e-4):
// KVBLK=128 staging, two 64-kv compute halves per staged tile, 4 waves,
// QBLK=32/wave, 512 blocks, 80 KB LDS. Pure-f16 MFMA, exp2-folded scores,
// lsum via ones-MFMA, P via per-wave LDS, XCD swizzle, setprio.
// ---------------------------------------------------------------------------
__global__ __launch_bounds__(256, 2) void attn_kernel(
    const f16* __restrict__ QhG, const f16* __restrict__ KhG,
    const f16* __restrict__ VhG, f16* __restrict__ OhG)
{
    __shared__ __align__(16) f16 lds[2][2][8192];   // 64 KB: Kh, Vh dbuf (128 kv)
    __shared__ __align__(16) f16 PL[4][2][1024];    // 16 KB per-wave P^T

    const int tid = threadIdx.x;
    const int l   = tid & 63;
    const int w   = tid >> 6;
    const int fr  = l & 15;
    const int g   = l >> 4;
    const int fk  = g * 8;
    const int rg  = g * 4;
    const int swz = (fr & 7) << 3;

    // 512 blocks, 64-block chunks per XCD (4 bh -> 2 MB K+V per XCD L2)
    const int lin  = blockIdx.x + 16 * (blockIdx.y + 16 * blockIdx.z);
    const int sid  = (lin & 7) * 64 + (lin >> 3);
    const int qblk = sid & 15;
    const int head = (sid >> 4) & 15;
    const int batch = sid >> 8;

    const int q0 = qblk * 128;
    const size_t rowbase = (size_t)batch * SEQ;
    const int hcol = head * HD;
    const size_t bhbase = ((size_t)batch * HEADS + head) * (size_t)(SEQ * HD);

    size_t kA[4], vA[4];
    #pragma unroll
    for (int c = 0; c < 4; ++c) {
        const int h0 = (w * 4 + c) * 512 + l * 8;
        kA[c] = bhbase + (size_t)h0;                               // + t*8192
        vA[c] = bhbase + (size_t)(h0 >> 7) * 2048 + (h0 & 127);    // + t*128
    }

#define STAGE(B, T) do {                                                    \
        const size_t _ko = (size_t)(T) * 8192;                              \
        const size_t _vo = (size_t)(T) * 128;                               \
        _Pragma("unroll")                                                   \
        for (int c = 0; c < 4; ++c) {                                       \
            const int lo_ = (w * 4 + c) * 512;                              \
            glds16(KhG + kA[c] + _ko, &lds[B][0][lo_]);                     \
            glds16(VhG + vA[c] + _vo, &lds[B][1][lo_]);                     \
        }                                                                   \
    } while (0)

    STAGE(0, 0);

    // Q fragments (B operand, f16, pre-scaled by log2e/64)
    f16x8 qh[2][2];
    #pragma unroll
    for (int qb = 0; qb < 2; ++qb) {
        const f16* qp = &QhG[(rowbase + q0 + w * 32 + qb * 16 + fr) * DIM + hcol];
        qh[qb][0] = *reinterpret_cast<const f16x8*>(&qp[fk]);
        qh[qb][1] = *reinterpret_cast<const f16x8*>(&qp[32 + fk]);
    }

    f16x8 onesv;
    #pragma unroll
    for (int i = 0; i < 8; ++i) onesv[i] = (f16)1.0f;

    f32x4 ls[2] = {};
    f32x4 oa[4][2] = {};

    int cur = 0;
    for (int t = 0; t < NT2; ++t) {
        asm volatile("s_waitcnt vmcnt(0) lgkmcnt(0)\ns_barrier" ::: "memory");
        if (t + 1 < NT2) STAGE(cur ^ 1, t + 1);

        #pragma unroll
        for (int hh = 0; hh < 2; ++hh) {     // two 64-kv halves
            const f16* Kh = &lds[cur][0][hh * 4096];
            const f16* Vh = &lds[cur][1][hh * 64];

            // ---- S'^T = K Q'^T ----
            f32x4 sa[4][2] = {};
            __builtin_amdgcn_s_setprio(1);
            #pragma unroll
            for (int kvb = 0; kvb < 4; ++kvb) {
                #pragma unroll
                for (int ks = 0; ks < 2; ++ks) {
                    const int o = ((kvb * 16 + fr) * 64 + ks * 32 + fk) ^ swz;
                    const f16x8 kh = *reinterpret_cast<const f16x8*>(&Kh[o]);
                    sa[kvb][0] = MFMA16(kh, qh[0][ks], sa[kvb][0]);
                    sa[kvb][1] = MFMA16(kh, qh[1][ks], sa[kvb][1]);
                }
            }
            __builtin_amdgcn_s_setprio(0);

            // ---- P = 2^s per q-stream, pack, stash in per-wave LDS ----
            f16x8 pf[2][2];
            #pragma unroll
            for (int qb = 0; qb < 2; ++qb) {
                f16* Wh = &PL[w][qb][0];
                #pragma unroll
                for (int kvb = 0; kvb < 4; ++kvb) {
                    const f16x2 p01 = pk_f16(exp2_hw(sa[kvb][qb][0]),
                                             exp2_hw(sa[kvb][qb][1]));
                    const f16x2 p23 = pk_f16(exp2_hw(sa[kvb][qb][2]),
                                             exp2_hw(sa[kvb][qb][3]));
                    f16x4 h4;
                    h4[0] = p01[0]; h4[1] = p01[1]; h4[2] = p23[0]; h4[3] = p23[1];
                    const int po = (fr * 64 + kvb * 16 + rg) ^ swz;
                    *reinterpret_cast<f16x4*>(&Wh[po]) = h4;
                }
                #pragma unroll
                for (int ks = 0; ks < 2; ++ks) {
                    const int ro = (fr * 64 + ks * 32 + fk) ^ swz;
                    pf[qb][ks] = *reinterpret_cast<const f16x8*>(&Wh[ro]);
                }
            }

            // ---- lsum += colsum(P); O^T += V^T P^T ----
            __builtin_amdgcn_s_setprio(1);
            #pragma unroll
            for (int qb = 0; qb < 2; ++qb)
                #pragma unroll
                for (int ks = 0; ks < 2; ++ks)
                    ls[qb] = MFMA16(onesv, pf[qb][ks], ls[qb]);
            #pragma unroll
            for (int db = 0; db < 4; ++db) {
                #pragma unroll
                for (int ks = 0; ks < 2; ++ks) {
                    const int vo = (db * 16 + fr) * 128 + ((ks * 32 + fk) ^ swz);
                    const f16x8 vh = *reinterpret_cast<const f16x8*>(&Vh[vo]);
                    oa[db][0] = MFMA16(vh, pf[0][ks], oa[db][0]);
                    oa[db][1] = MFMA16(vh, pf[1][ks], oa[db][1]);
                }
            }
            __builtin_amdgcn_s_setprio(0);
        }
        cur ^= 1;
    }
#undef STAGE

    // ---- epilogue: O hi plane (swizzled for oproj staging) ----
    #pragma unroll
    for (int qb = 0; qb < 2; ++qb) {
        const float inv = 1.0f / ls[qb][0];
        const size_t row = rowbase + q0 + w * 32 + qb * 16 + fr;
        const int s = ((int)row >> 1) & 3;
        #pragma unroll
        for (int db = 0; db < 4; ++db) {
            f16x4 h4;
            #pragma unroll
            for (int j = 0; j < 4; ++j) h4[j] = (f16)(oa[db][qb][j] * inv);
            const int kg = hcol + db * 16 + rg;
            const size_t o = row * DIM + (kg & ~31) + ((kg & 31) ^ (s << 3));
            *reinterpret_cast<f16x4*>(&OhG[o]) = h4;
        }
    }
}

extern "C" void kernel_launch(void* const* d_in, const int* in_sizes, int n_in,
                              void* d_out, int out_size, void* d_ws, size_t ws_size,
                              hipStream_t stream)
{
    const float* x  = (const float*)d_in[0];
    const float* Wq = (const float*)d_in[1];
    const float* bq = (const float*)d_in[2];
    const float* Wk = (const float*)d_in[3];
    const float* bk = (const float*)d_in[4];
    const float* Wv = (const float*)d_in[5];
    const float* bv = (const float*)d_in[6];
    const float* Wo = (const float*)d_in[7];
    const float* bo = (const float*)d_in[8];
    float* out = (float*)d_out;

    const size_t PS = (size_t)MTOT * DIM;   // 4,194,304 elements
    f16* QhG = (f16*)d_ws;                  // 8 MB each
    f16* KhG = QhG + PS;
    f16* VhG = KhG + PS;
    f16* XhG = VhG + PS;                    // reused as Oh after qkv
    f16* WqH = XhG + PS;                    // 2 MB each below
    f16* WkH = WqH + (size_t)DIM * DIM;
    f16* WvH = WkH + (size_t)DIM * DIM;
    f16* WoH = WvH + (size_t)DIM * DIM;
    f16* OhG = XhG;                         // alias: x consumed before attn

    presplit_kernel<<<8192, 256, 0, stream>>>(x, Wq, Wk, Wv, Wo,
                                              XhG, WqH, WkH, WvH, WoH);

    dim3 gqkv(DIM / 128, MTOT / 128, 3);
    qkv_kernel<<<gqkv, 256, 0, stream>>>(XhG, WqH, bq, WkH, bk, WvH, bv,
                                         QhG, KhG, VhG);

    dim3 gattn(SEQ / 128, HEADS, BATCH);
    attn_kernel<<<gattn, 256, 0, stream>>>(QhG, KhG, VhG, OhG);

    dim3 gout(DIM / 128, MTOT / 128);
    oproj_kernel<<<gout, 256, 0, stream>>>(OhG, WoH, bo, out);
}

// Round 15
// 115.888 us; speedup vs baseline: 1.1410x; 1.0758x over previous
//
#include <hip/hip_runtime.h>
#include <math.h>

typedef _Float16 f16;
typedef _Float16 f16x2 __attribute__((ext_vector_type(2)));
typedef _Float16 f16x4 __attribute__((ext_vector_type(4)));
typedef _Float16 f16x8 __attribute__((ext_vector_type(8)));
typedef float    f32x4 __attribute__((ext_vector_type(4)));

constexpr int DIM   = 1024;
constexpr int HEADS = 16;
constexpr int HD    = 64;
constexpr int BATCH = 2;
constexpr int SEQ   = 2048;
constexpr int MTOT  = BATCH * SEQ;   // 4096
constexpr int NT2   = SEQ / 128;     // 16 staged KV tiles of 128

// exp(q.k/64) == exp2((q * log2e/64) . k): fold into Q projection scale.
#define QSCALE (1.4426950408889634f / 64.0f)

#define MFMA16(a, b, c) __builtin_amdgcn_mfma_f32_16x16x32_f16((a), (b), (c), 0, 0, 0)

__device__ __forceinline__ void glds16(const void* g, void* l) {
    __builtin_amdgcn_global_load_lds(
        (const __attribute__((address_space(1))) void*)g,
        (__attribute__((address_space(3))) void*)l, 16, 0, 0);
}

__device__ __forceinline__ float exp2_hw(float x) {
    float r;
    asm("v_exp_f32 %0, %1" : "=v"(r) : "v"(x));   // D = 2^S0
    return r;
}

__device__ __forceinline__ f16x2 pk_f16(float a, float b) {
    return __builtin_bit_cast(f16x2, __builtin_amdgcn_cvt_pkrtz(a, b));
}

// ---------------------------------------------------------------------------
// Pre-split pass: fp32 -> f16 hi planes, GEMM fragment-read swizzle baked:
// within each 32-half k-tile, 8-half slot ^= ((row>>1)&3).
// ---------------------------------------------------------------------------
__global__ __launch_bounds__(256) void presplit_kernel(
    const float* __restrict__ x,  const float* __restrict__ Wq,
    const float* __restrict__ Wk, const float* __restrict__ Wv,
    const float* __restrict__ Wo,
    f16* __restrict__ Xh,  f16* __restrict__ WqH, f16* __restrict__ WkH,
    f16* __restrict__ WvH, f16* __restrict__ WoH)
{
    const int bid = blockIdx.x;
    const float* src; f16* dh; int row;
    if (bid < 4096)      { src = x;  dh = Xh;  row = bid; }
    else if (bid < 5120) { src = Wq; dh = WqH; row = bid - 4096; }
    else if (bid < 6144) { src = Wk; dh = WkH; row = bid - 5120; }
    else if (bid < 7168) { src = Wv; dh = WvH; row = bid - 6144; }
    else                 { src = Wo; dh = WoH; row = bid - 7168; }

    const int k = threadIdx.x * 4;
    const float4 v = *reinterpret_cast<const float4*>(&src[(size_t)row * DIM + k]);
    const int s = (row >> 1) & 3;
    const size_t o = (size_t)row * DIM + (k & ~31) + ((k & 31) ^ (s << 3));
    f16x4 h4;
    h4[0] = (f16)v.x; h4[1] = (f16)v.y; h4[2] = (f16)v.z; h4[3] = (f16)v.w;
    *reinterpret_cast<f16x4*>(&dh[o]) = h4;
}

// ---------------------------------------------------------------------------
// 1-term plane GEMM, BK=32 (R12 proven layout), T4 counted-vmcnt dbuf:
// per k-step {GSTAGE(next); vmcnt(4); s_barrier; ds_read+MFMA; s_barrier}.
// Raw barriers (no __syncthreads drain) keep next-tile loads in flight.
// BM=BN=128, 4 waves, LDS 2x16 KB dbuf.
// MODE 0: C=(acc+bias)*scale -> fp32.   MODE 3: F=(acc+bias)*scale -> f16.
// MODE 1: K hi plane [bh][kv][ d ^ ((kv&7)<<3) ]  (transposed compute)
// MODE 2: V hi plane [bh][d][ kv ^ ((d&7)<<3) ]
// ---------------------------------------------------------------------------
template <int MODE>
__device__ __forceinline__ void gemm_plane_body(
    const f16* __restrict__ AhG, const f16* __restrict__ BhG,
    const float* __restrict__ bias, float* __restrict__ C,
    f16* __restrict__ F, float scale, f16* __restrict__ smem)
{
    const int tid = threadIdx.x;
    const int l   = tid & 63;
    const int w   = tid >> 6;
    const int wm  = (w >> 1) * 64;
    const int wn  = (w & 1) * 64;
    const int m0  = blockIdx.y * 128;
    const int n0  = blockIdx.x * 128;
    const int fr  = l & 15;
    const int fk  = (l >> 4) * 8;
    const int rg  = (l >> 4) * 4;
    const int fko = fk ^ (((fr >> 1) & 3) << 3);   // swizzled k-slot

    f32x4 acc[4][4] = {};

#define GSTAGE(B, K0) do {                                                  \
        _Pragma("unroll")                                                   \
        for (int j = 0; j < 4; ++j) {                                       \
            const int c = w * 4 + j;             /* 0..15 */                \
            const int p = c >> 3;                /* 0 = A, 1 = B */         \
            const f16* P = (p == 0) ? AhG : BhG;                            \
            const int r0 = (p == 0) ? m0 : n0;                              \
            const int row = r0 + (c & 7) * 16 + (l >> 2);                   \
            glds16(P + (size_t)row * DIM + (K0) + (l & 3) * 8,              \
                   smem + (B) * 8192 + c * 512);                            \
        }                                                                   \
    } while (0)

    GSTAGE(0, 0);
    int cur = 0;

    for (int k0 = 0; k0 < DIM; k0 += 32) {
        if (k0 + 32 < DIM) {
            GSTAGE(cur ^ 1, k0 + 32);   // 4 loads/wave for next tile in flight
            asm volatile("s_waitcnt vmcnt(4)\ns_barrier" ::: "memory");
        } else {
            asm volatile("s_waitcnt vmcnt(0)\ns_barrier" ::: "memory");
        }

        const f16* Ah = smem + cur * 8192;
        const f16* Bh = Ah + 4096;

        f16x8 ah[4], bh[4];
        #pragma unroll
        for (int m = 0; m < 4; ++m)
            ah[m] = *reinterpret_cast<const f16x8*>(&Ah[(wm + m * 16 + fr) * 32 + fko]);
        #pragma unroll
        for (int n = 0; n < 4; ++n)
            bh[n] = *reinterpret_cast<const f16x8*>(&Bh[(wn + n * 16 + fr) * 32 + fko]);
        #pragma unroll
        for (int n = 0; n < 4; ++n)
            #pragma unroll
            for (int m = 0; m < 4; ++m) {
                if (MODE == 1)   // transposed: D[d][token]
                    acc[m][n] = MFMA16(bh[n], ah[m], acc[m][n]);
                else
                    acc[m][n] = MFMA16(ah[m], bh[n], acc[m][n]);
            }
        // reads of cur consumed (MFMA reg deps force lgkm waits); barrier
        // before next iteration may overwrite cur's buffer
        asm volatile("s_barrier" ::: "memory");
        cur ^= 1;
    }
#undef GSTAGE

    if (MODE == 0 || MODE == 3) {
        #pragma unroll
        for (int n = 0; n < 4; ++n) {
            const int col  = n0 + wn + n * 16 + fr;
            const float bb = bias[col];
            #pragma unroll
            for (int m = 0; m < 4; ++m) {
                #pragma unroll
                for (int r = 0; r < 4; ++r) {
                    const int row = m0 + wm + m * 16 + rg + r;
                    const float v = (acc[m][n][r] + bb) * scale;
                    if (MODE == 0) C[(size_t)row * DIM + col] = v;
                    else           F[(size_t)row * DIM + col] = (f16)v;
                }
            }
        }
    } else if (MODE == 1) {
        constexpr int RS = 72;
        const int batch = m0 >> 11;
        const int kvg0  = m0 & 2047;
        for (int s = 0; s < 2; ++s) {
            __syncthreads();
            if ((w & 1) == s) {
                #pragma unroll
                for (int n = 0; n < 4; ++n) {
                    #pragma unroll
                    for (int m = 0; m < 4; ++m) {
                        const int kvrow = wm + m * 16 + fr;
                        const int dd    = n * 16 + rg;
                        f16x4 h4;
                        #pragma unroll
                        for (int r = 0; r < 4; ++r)
                            h4[r] = (f16)(acc[m][n][r] + bias[n0 + wn + dd + r]);
                        const int o = kvrow * RS + (dd ^ ((kvrow & 7) << 3));
                        *reinterpret_cast<f16x4*>(&smem[o]) = h4;
                    }
                }
            }
            __syncthreads();
            const size_t bh_ = (size_t)batch * HEADS + (n0 >> 6) + s;
            const int row = tid >> 1, c0 = (tid & 1) * 32;
            #pragma unroll
            for (int j = 0; j < 4; ++j) {
                const int so = row * RS + c0 + j * 8;
                const size_t go = bh_ * 131072 + (size_t)(kvg0 + row) * 64 + c0 + j * 8;
                *reinterpret_cast<f16x8*>(&F[go]) =
                    *reinterpret_cast<const f16x8*>(&smem[so]);
            }
        }
    } else {
        constexpr int RS = 136;
        const int batch = m0 >> 11;
        const int kvg0  = m0 & 2047;
        for (int s = 0; s < 2; ++s) {
            __syncthreads();
            if ((w & 1) == s) {
                #pragma unroll
                for (int n = 0; n < 4; ++n) {
                    const int d    = n * 16 + fr;
                    const float bb = bias[n0 + wn + d];
                    #pragma unroll
                    for (int m = 0; m < 4; ++m) {
                        const int kvl = wm + m * 16 + rg;
                        f16x4 h4;
                        h4[0] = (f16)(acc[m][n][0] + bb);
                        h4[1] = (f16)(acc[m][n][1] + bb);
                        h4[2] = (f16)(acc[m][n][2] + bb);
                        h4[3] = (f16)(acc[m][n][3] + bb);
                        const int o = d * RS + (kvl ^ ((d & 7) << 3));
                        *reinterpret_cast<f16x4*>(&smem[o]) = h4;
                    }
                }
            }
            __syncthreads();
            const size_t bh_ = (size_t)batch * HEADS + (n0 >> 6) + s;
            const int row = tid >> 2, c0 = (tid & 3) * 32;
            #pragma unroll
            for (int j = 0; j < 4; ++j) {
                const int so = row * RS + c0 + j * 8;
                const size_t go = bh_ * 131072 + (size_t)row * 2048 + kvg0 + c0 + j * 8;
                *reinterpret_cast<f16x8*>(&F[go]) =
                    *reinterpret_cast<const f16x8*>(&smem[so]);
            }
        }
    }
}

__global__ __launch_bounds__(256) void qkv_kernel(
    const f16* __restrict__ XhG,
    const f16* __restrict__ WqH, const float* __restrict__ bq,
    const f16* __restrict__ WkH, const float* __restrict__ bk,
    const f16* __restrict__ WvH, const float* __restrict__ bv,
    f16* __restrict__ QhG, f16* __restrict__ KhG, f16* __restrict__ VhG)
{
    __shared__ __align__(16) f16 smem[18432];  // 36 KB (dbuf 32 KB; K-repack 18 KB)
    if (blockIdx.z == 0)
        gemm_plane_body<3>(XhG, WqH, bq, nullptr, QhG, QSCALE, smem);
    else if (blockIdx.z == 1)
        gemm_plane_body<1>(XhG, WkH, bk, nullptr, KhG, 1.0f, smem);
    else
        gemm_plane_body<2>(XhG, WvH, bv, nullptr, VhG, 1.0f, smem);
}

__global__ __launch_bounds__(256) void oproj_kernel(
    const f16* __restrict__ OhG, const f16* __restrict__ WoH,
    const float* __restrict__ bo, float* __restrict__ out)
{
    __shared__ __align__(16) f16 smem[16384];  // 32 KB dbuf
    gemm_plane_body<0>(OhG, WoH, bo, out, nullptr, 1.0f, smem);
}

// ---------------------------------------------------------------------------
// Flash attention v9 (unchanged, proven 48.8 us / 4.88e-4):
// KVBLK=128 staging, two 64-kv compute halves per staged tile, 4 waves,
// QBLK=32/wave, 512 blocks, 80 KB LDS. Pure-f16 MFMA, exp2-folded scores,
// lsum via ones-MFMA, P via per-wave LDS, XCD swizzle, setprio.
// ---------------------------------------------------------------------------
__global__ __launch_bounds__(256, 2) void attn_kernel(
    const f16* __restrict__ QhG, const f16* __restrict__ KhG,
    const f16* __restrict__ VhG, f16* __restrict__ OhG)
{
    __shared__ __align__(16) f16 lds[2][2][8192];   // 64 KB: Kh, Vh dbuf (128 kv)
    __shared__ __align__(16) f16 PL[4][2][1024];    // 16 KB per-wave P^T

    const int tid = threadIdx.x;
    const int l   = tid & 63;
    const int w   = tid >> 6;
    const int fr  = l & 15;
    const int g   = l >> 4;
    const int fk  = g * 8;
    const int rg  = g * 4;
    const int swz = (fr & 7) << 3;

    // 512 blocks, 64-block chunks per XCD (4 bh -> 2 MB K+V per XCD L2)
    const int lin  = blockIdx.x + 16 * (blockIdx.y + 16 * blockIdx.z);
    const int sid  = (lin & 7) * 64 + (lin >> 3);
    const int qblk = sid & 15;
    const int head = (sid >> 4) & 15;
    const int batch = sid >> 8;

    const int q0 = qblk * 128;
    const size_t rowbase = (size_t)batch * SEQ;
    const int hcol = head * HD;
    const size_t bhbase = ((size_t)batch * HEADS + head) * (size_t)(SEQ * HD);

    size_t kA[4], vA[4];
    #pragma unroll
    for (int c = 0; c < 4; ++c) {
        const int h0 = (w * 4 + c) * 512 + l * 8;
        kA[c] = bhbase + (size_t)h0;                               // + t*8192
        vA[c] = bhbase + (size_t)(h0 >> 7) * 2048 + (h0 & 127);    // + t*128
    }

#define STAGE(B, T) do {                                                    \
        const size_t _ko = (size_t)(T) * 8192;                              \
        const size_t _vo = (size_t)(T) * 128;                               \
        _Pragma("unroll")                                                   \
        for (int c = 0; c < 4; ++c) {                                       \
            const int lo_ = (w * 4 + c) * 512;                              \
            glds16(KhG + kA[c] + _ko, &lds[B][0][lo_]);                     \
            glds16(VhG + vA[c] + _vo, &lds[B][1][lo_]);                     \
        }                                                                   \
    } while (0)

    STAGE(0, 0);

    // Q fragments (B operand, f16, pre-scaled by log2e/64)
    f16x8 qh[2][2];
    #pragma unroll
    for (int qb = 0; qb < 2; ++qb) {
        const f16* qp = &QhG[(rowbase + q0 + w * 32 + qb * 16 + fr) * DIM + hcol];
        qh[qb][0] = *reinterpret_cast<const f16x8*>(&qp[fk]);
        qh[qb][1] = *reinterpret_cast<const f16x8*>(&qp[32 + fk]);
    }

    f16x8 onesv;
    #pragma unroll
    for (int i = 0; i < 8; ++i) onesv[i] = (f16)1.0f;

    f32x4 ls[2] = {};
    f32x4 oa[4][2] = {};

    int cur = 0;
    for (int t = 0; t < NT2; ++t) {
        asm volatile("s_waitcnt vmcnt(0) lgkmcnt(0)\ns_barrier" ::: "memory");
        if (t + 1 < NT2) STAGE(cur ^ 1, t + 1);

        #pragma unroll
        for (int hh = 0; hh < 2; ++hh) {     // two 64-kv halves
            const f16* Kh = &lds[cur][0][hh * 4096];
            const f16* Vh = &lds[cur][1][hh * 64];

            // ---- S'^T = K Q'^T ----
            f32x4 sa[4][2] = {};
            __builtin_amdgcn_s_setprio(1);
            #pragma unroll
            for (int kvb = 0; kvb < 4; ++kvb) {
                #pragma unroll
                for (int ks = 0; ks < 2; ++ks) {
                    const int o = ((kvb * 16 + fr) * 64 + ks * 32 + fk) ^ swz;
                    const f16x8 kh = *reinterpret_cast<const f16x8*>(&Kh[o]);
                    sa[kvb][0] = MFMA16(kh, qh[0][ks], sa[kvb][0]);
                    sa[kvb][1] = MFMA16(kh, qh[1][ks], sa[kvb][1]);
                }
            }
            __builtin_amdgcn_s_setprio(0);

            // ---- P = 2^s per q-stream, pack, stash in per-wave LDS ----
            f16x8 pf[2][2];
            #pragma unroll
            for (int qb = 0; qb < 2; ++qb) {
                f16* Wh = &PL[w][qb][0];
                #pragma unroll
                for (int kvb = 0; kvb < 4; ++kvb) {
                    const f16x2 p01 = pk_f16(exp2_hw(sa[kvb][qb][0]),
                                             exp2_hw(sa[kvb][qb][1]));
                    const f16x2 p23 = pk_f16(exp2_hw(sa[kvb][qb][2]),
                                             exp2_hw(sa[kvb][qb][3]));
                    f16x4 h4;
                    h4[0] = p01[0]; h4[1] = p01[1]; h4[2] = p23[0]; h4[3] = p23[1];
                    const int po = (fr * 64 + kvb * 16 + rg) ^ swz;
                    *reinterpret_cast<f16x4*>(&Wh[po]) = h4;
                }
                #pragma unroll
                for (int ks = 0; ks < 2; ++ks) {
                    const int ro = (fr * 64 + ks * 32 + fk) ^ swz;
                    pf[qb][ks] = *reinterpret_cast<const f16x8*>(&Wh[ro]);
                }
            }

            // ---- lsum += colsum(P); O^T += V^T P^T ----
            __builtin_amdgcn_s_setprio(1);
            #pragma unroll
            for (int qb = 0; qb < 2; ++qb)
                #pragma unroll
                for (int ks = 0; ks < 2; ++ks)
                    ls[qb] = MFMA16(onesv, pf[qb][ks], ls[qb]);
            #pragma unroll
            for (int db = 0; db < 4; ++db) {
                #pragma unroll
                for (int ks = 0; ks < 2; ++ks) {
                    const int vo = (db * 16 + fr) * 128 + ((ks * 32 + fk) ^ swz);
                    const f16x8 vh = *reinterpret_cast<const f16x8*>(&Vh[vo]);
                    oa[db][0] = MFMA16(vh, pf[0][ks], oa[db][0]);
                    oa[db][1] = MFMA16(vh, pf[1][ks], oa[db][1]);
                }
            }
            __builtin_amdgcn_s_setprio(0);
        }
        cur ^= 1;
    }
#undef STAGE

    // ---- epilogue: O hi plane (swizzled for oproj staging) ----
    #pragma unroll
    for (int qb = 0; qb < 2; ++qb) {
        const float inv = 1.0f / ls[qb][0];
        const size_t row = rowbase + q0 + w * 32 + qb * 16 + fr;
        const int s = ((int)row >> 1) & 3;
        #pragma unroll
        for (int db = 0; db < 4; ++db) {
            f16x4 h4;
            #pragma unroll
            for (int j = 0; j < 4; ++j) h4[j] = (f16)(oa[db][qb][j] * inv);
            const int kg = hcol + db * 16 + rg;
            const size_t o = row * DIM + (kg & ~31) + ((kg & 31) ^ (s << 3));
            *reinterpret_cast<f16x4*>(&OhG[o]) = h4;
        }
    }
}

extern "C" void kernel_launch(void* const* d_in, const int* in_sizes, int n_in,
                              void* d_out, int out_size, void* d_ws, size_t ws_size,
                              hipStream_t stream)
{
    const float* x  = (const float*)d_in[0];
    const float* Wq = (const float*)d_in[1];
    const float* bq = (const float*)d_in[2];
    const float* Wk = (const float*)d_in[3];
    const float* bk = (const float*)d_in[4];
    const float* Wv = (const float*)d_in[5];
    const float* bv = (const float*)d_in[6];
    const float* Wo = (const float*)d_in[7];
    const float* bo = (const float*)d_in[8];
    float* out = (float*)d_out;

    const size_t PS = (size_t)MTOT * DIM;   // 4,194,304 elements
    f16* QhG = (f16*)d_ws;                  // 8 MB each
    f16* KhG = QhG + PS;
    f16* VhG = KhG + PS;
    f16* XhG = VhG + PS;                    // reused as Oh after qkv
    f16* WqH = XhG + PS;                    // 2 MB each below
    f16* WkH = WqH + (size_t)DIM * DIM;
    f16* WvH = WkH + (size_t)DIM * DIM;
    f16* WoH = WvH + (size_t)DIM * DIM;
    f16* OhG = XhG;                         // alias: x consumed before attn

    presplit_kernel<<<8192, 256, 0, stream>>>(x, Wq, Wk, Wv, Wo,
                                              XhG, WqH, WkH, WvH, WoH);

    dim3 gqkv(DIM / 128, MTOT / 128, 3);
    qkv_kernel<<<gqkv, 256, 0, stream>>>(XhG, WqH, bq, WkH, bk, WvH, bv,
                                         QhG, KhG, VhG);

    dim3 gattn(SEQ / 128, HEADS, BATCH);
    attn_kernel<<<gattn, 256, 0, stream>>>(QhG, KhG, VhG, OhG);

    dim3 gout(DIM / 128, MTOT / 128);
    oproj_kernel<<<gout, 256, 0, stream>>>(OhG, WoH, bo, out);
}